// Round 10
// baseline (512.271 us; speedup 1.0000x reference)
//
#include <hip/hip_runtime.h>
#include <stdint.h>

typedef float  f32x4  __attribute__((ext_vector_type(4)));
typedef short  bf16x8 __attribute__((ext_vector_type(8)));

#define TYPES 10
#define D_IN  128
#define D_H1  512
#define D_H2  512
#define D_OUT 256

__device__ __forceinline__ unsigned short f2bf(float f) {
  union { float f; unsigned u; } v; v.f = f;
  unsigned u = v.u;
  return (unsigned short)((u + 0x7FFFu + ((u >> 16) & 1u)) >> 16);  // RTNE
}

__device__ __forceinline__ void async16(void* lds, const void* g) {
  __builtin_amdgcn_global_load_lds(
      (const __attribute__((address_space(1))) void*)g,
      (__attribute__((address_space(3))) void*)lds, 16, 0, 0);
}

__global__ void k_init(int* meta) {
  if (threadIdx.x < 48) meta[threadIdx.x] = 0;
}

__global__ void k_hist(const int* __restrict__ types, int n, int* __restrict__ meta) {
  __shared__ int lc[TYPES];
  if (threadIdx.x < TYPES) lc[threadIdx.x] = 0;
  __syncthreads();
  int i = blockIdx.x * 256 + threadIdx.x;
  if (i < n) atomicAdd(&lc[types[i]], 1);
  __syncthreads();
  if (threadIdx.x < TYPES && lc[threadIdx.x]) atomicAdd(&meta[threadIdx.x], lc[threadIdx.x]);
}

__global__ void k_scan(int* meta) {
  if (threadIdx.x == 0) {
    int off = 0;
    for (int t = 0; t < TYPES; ++t) {
      meta[16 + t] = off;
      off += ((meta[t] + 255) >> 8) << 8;
    }
    meta[26] = off;
  }
}

__global__ void k_scatter(const int* __restrict__ types, int n,
                          int* __restrict__ meta, int* __restrict__ perm) {
  __shared__ int lc[TYPES], lbase[TYPES];
  if (threadIdx.x < TYPES) lc[threadIdx.x] = 0;
  __syncthreads();
  int i = blockIdx.x * 256 + threadIdx.x;
  int t = 0, loc = 0;
  bool ok = i < n;
  if (ok) { t = types[i]; loc = atomicAdd(&lc[t], 1); }
  __syncthreads();
  if (threadIdx.x < TYPES) {
    int c = lc[threadIdx.x];
    lbase[threadIdx.x] = c ? atomicAdd(&meta[32 + threadIdx.x], c) : 0;
  }
  __syncthreads();
  if (ok) perm[meta[16 + t] + lbase[t] + loc] = i;
}

__global__ void k_gather(const float* __restrict__ x, const int* __restrict__ perm,
                         const int* __restrict__ meta, unsigned short* __restrict__ xs) {
  int p = blockIdx.x * 8 + (threadIdx.x >> 5);
  if (p >= meta[26]) return;
  int t = 0;
  while (p >= meta[17 + t]) t++;
  int e = (threadIdx.x & 31) * 4;
  unsigned short o0, o1, o2, o3;
  if (p - meta[16 + t] < meta[t]) {
    const float4 v = *(const float4*)(x + (size_t)perm[p] * D_IN + e);
    o0 = f2bf(v.x); o1 = f2bf(v.y); o2 = f2bf(v.z); o3 = f2bf(v.w);
  } else {
    o0 = o1 = o2 = o3 = 0;
  }
  *(ushort4*)(xs + (size_t)p * D_IN + e) = make_ushort4(o0, o1, o2, o3);
}

__global__ void k_wtrans_all(const float* __restrict__ W0a, const float* __restrict__ W1a,
                             const float* __restrict__ W2a,
                             unsigned short* __restrict__ wt0, unsigned short* __restrict__ wt1,
                             unsigned short* __restrict__ wt2) {
  int b = blockIdx.x;
  const float* W; unsigned short* Wt; int K, NOUT, t, local;
  if (b < 160)      { W = W0a; Wt = wt0; K = 128; NOUT = 512; t = b / 16; local = b % 16; }
  else if (b < 800) { b -= 160; W = W1a; Wt = wt1; K = 512; NOUT = 512; t = b / 64; local = b % 64; }
  else              { b -= 800; W = W2a; Wt = wt2; K = 512; NOUT = 256; t = b / 32; local = b % 32; }
  int ntn = NOUT >> 6;
  int kb = local / ntn, nb = local % ntn;
  __shared__ unsigned short tile[64][65];
  const float* src = W + (size_t)t * K * NOUT + (size_t)(kb * 64) * NOUT + nb * 64;
  int c = threadIdx.x & 63;
  int r0 = threadIdx.x >> 6;
  #pragma unroll
  for (int i = 0; i < 16; ++i) {
    int r = r0 * 16 + i;
    tile[r][c] = f2bf(src[(size_t)r * NOUT + c]);
  }
  __syncthreads();
  unsigned short* dst = Wt + (size_t)t * NOUT * K + (size_t)(nb * 64) * K + kb * 64;
  #pragma unroll
  for (int i = 0; i < 16; ++i) {
    int nn = r0 * 16 + i;
    dst[(size_t)nn * K + c] = tile[c][nn];
  }
}

// ---------------------------------------------------------------------------
// Production grouped GEMM: byte-identical to R9 (passed, 433us).
// ---------------------------------------------------------------------------
template <int K, int NOUT, bool RELU, bool FINAL>
__launch_bounds__(512, 2)
__global__ void k_gemm(const unsigned short* __restrict__ A,
                       const unsigned short* __restrict__ Wt,
                       const float* __restrict__ bias,
                       unsigned short* __restrict__ H,
                       float* __restrict__ OUT,
                       const int* __restrict__ meta,
                       const int* __restrict__ perm) {
  constexpr int nKT = K / 64;
  __shared__ char lds[131072];

  int NXB = gridDim.x;
  int nwg = NXB * (int)gridDim.y;
  int raw = blockIdx.x + blockIdx.y * NXB;
  int q = nwg >> 3, rr = nwg & 7;
  int xcd = raw & 7, idx = raw >> 3;
  int swz = (xcd < rr ? xcd * (q + 1) : rr * (q + 1) + (xcd - rr) * q) + idx;
  int bx = swz % NXB, by = swz / NXB;

  int row0 = by * 256;
  if (row0 >= meta[26]) return;
  int t = 0;
  while (row0 >= meta[17 + t]) t++;
  int seg = meta[16 + t], cnt = meta[t];
  int tid = threadIdx.x, lane = tid & 63, wid = tid >> 6;
  int wr = (wid >> 2) * 128, wc = (wid & 3) * 64;
  int col0 = bx * 256;
  const char* Ag = (const char*)(A + (size_t)row0 * K);
  const char* Bg = (const char*)(Wt + ((size_t)t * NOUT + col0) * K);

  int gsrc = ((tid & 7) ^ ((tid >> 3) & 7)) * 16;
  const char* aS = Ag + (size_t)(tid >> 3) * (2 * K) + gsrc;
  const char* bS = Bg + (size_t)(((tid >> 3) & 31) + ((tid >> 3) >> 5) * 64) * (2 * K) + gsrc;

  auto stage = [&](int kt, int sub) {
    if (kt >= nKT) return;
    int h = sub & 1, du = kt & 1;
    char* dst = lds + ((sub < 2) ? 0 : 65536) + (du * 2 + h) * 16384 + wid * 1024;
    const char* src = (sub < 2 ? aS + (size_t)(h * 64) * (2 * K)
                               : bS + (size_t)(h * 32) * (2 * K)) + (size_t)kt * 128;
    async16(dst,        src);
    async16(dst + 8192, src + (size_t)128 * (2 * K));
  };

  f32x4 acc[8][4] = {};
  int rA = lane & 15, qoff = (lane >> 4) * 16, xr = (lane & 7) << 4;
  int lrA = (wid >> 2) * 64;
  int clB = (wid & 3) * 32;

  stage(0, 0); stage(0, 1); stage(0, 2); stage(0, 3); stage(1, 0);
  asm volatile("s_waitcnt vmcnt(2)" ::: "memory");
  __builtin_amdgcn_s_barrier();

  for (int g = 0; g < nKT; ++g) {
    int d = g & 1;
    const char* Ad = lds + d * 32768;
    const char* Bd = lds + 65536 + d * 32768;
    bf16x8 a[4][2], b0[2][2], b1[2][2];

    #pragma unroll
    for (int m = 0; m < 4; ++m) {
      int lr = lrA + m * 16 + rA;
      #pragma unroll
      for (int kk = 0; kk < 2; ++kk)
        a[m][kk] = *(const bf16x8*)(Ad + ((lr * 128 + kk * 64 + qoff) ^ xr));
    }
    #pragma unroll
    for (int nn = 0; nn < 2; ++nn) {
      int cl = clB + nn * 16 + rA;
      #pragma unroll
      for (int kk = 0; kk < 2; ++kk) {
        b0[nn][kk] = *(const bf16x8*)(Bd +         ((cl * 128 + kk * 64 + qoff) ^ xr));
        b1[nn][kk] = *(const bf16x8*)(Bd + 16384 + ((cl * 128 + kk * 64 + qoff) ^ xr));
      }
    }
    stage(g + 1, 1); stage(g + 1, 2); stage(g + 1, 3);
    __builtin_amdgcn_s_barrier();
    asm volatile("s_waitcnt lgkmcnt(0)" ::: "memory");
    __builtin_amdgcn_s_setprio(1);
    #pragma unroll
    for (int kk = 0; kk < 2; ++kk)
      #pragma unroll
      for (int m = 0; m < 4; ++m)
        #pragma unroll
        for (int nn = 0; nn < 2; ++nn) {
          acc[m][nn]     = __builtin_amdgcn_mfma_f32_16x16x32_bf16(a[m][kk], b0[nn][kk], acc[m][nn],     0, 0, 0);
          acc[m][2 + nn] = __builtin_amdgcn_mfma_f32_16x16x32_bf16(a[m][kk], b1[nn][kk], acc[m][2 + nn], 0, 0, 0);
        }
    __builtin_amdgcn_s_setprio(0);
    __builtin_amdgcn_s_barrier();

    #pragma unroll
    for (int m = 0; m < 4; ++m) {
      int lr = lrA + m * 16 + rA;
      #pragma unroll
      for (int kk = 0; kk < 2; ++kk)
        a[m][kk] = *(const bf16x8*)(Ad + 16384 + ((lr * 128 + kk * 64 + qoff) ^ xr));
    }
    stage(g + 2, 0);
    __builtin_amdgcn_s_barrier();
    asm volatile("s_waitcnt lgkmcnt(0)" ::: "memory");
    __builtin_amdgcn_s_setprio(1);
    #pragma unroll
    for (int kk = 0; kk < 2; ++kk)
      #pragma unroll
      for (int m = 0; m < 4; ++m)
        #pragma unroll
        for (int nn = 0; nn < 2; ++nn) {
          acc[4 + m][2 + nn] = __builtin_amdgcn_mfma_f32_16x16x32_bf16(a[m][kk], b1[nn][kk], acc[4 + m][2 + nn], 0, 0, 0);
          acc[4 + m][nn]     = __builtin_amdgcn_mfma_f32_16x16x32_bf16(a[m][kk], b0[nn][kk], acc[4 + m][nn],     0, 0, 0);
        }
    __builtin_amdgcn_s_setprio(0);
    if (g + 1 < nKT) {
      if (g + 2 < nKT) asm volatile("s_waitcnt vmcnt(2)" ::: "memory");
      else             asm volatile("s_waitcnt vmcnt(0)" ::: "memory");
    }
    __builtin_amdgcn_s_barrier();
  }

  int cA = lane & 15, rE = (lane >> 4) * 4;
  float bv[4];
  #pragma unroll
  for (int ni = 0; ni < 4; ++ni) bv[ni] = bias[t * NOUT + col0 + wc + ni * 16 + cA];
  char* cb = (char*)lds;

  if (!FINAL) {
    #pragma unroll
    for (int mi = 0; mi < 8; ++mi)
      #pragma unroll
      for (int e = 0; e < 4; ++e) {
        int row = wr + mi * 16 + rE + e;
        int sw = (row & 7) << 4;
        #pragma unroll
        for (int ni = 0; ni < 4; ++ni) {
          float v = acc[mi][ni][e] + bv[ni];
          if (RELU) v = fmaxf(v, 0.f);
          int col = wc + ni * 16 + cA;
          *(unsigned short*)(cb + ((row * 512 + col * 2) ^ sw)) = f2bf(v);
        }
      }
    __builtin_amdgcn_s_barrier();
    #pragma unroll 4
    for (int r = 0; r < 16; ++r) {
      int row = wid * 32 + r * 2 + (lane >> 5);
      int addr = row * 512 + ((((lane & 31) * 16)) ^ ((row & 7) << 4));
      bf16x8 v = *(const bf16x8*)(cb + addr);
      *(bf16x8*)(H + (size_t)(row0 + row) * NOUT + col0 + (lane & 31) * 8) = v;
    }
  } else {
    int myhalf = (wid & 3) >> 1;
    #pragma unroll
    for (int p = 0; p < 2; ++p) {
      if (myhalf == p) {
        int colh = wc & 127;
        #pragma unroll
        for (int mi = 0; mi < 8; ++mi)
          #pragma unroll
          for (int e = 0; e < 4; ++e) {
            int row = wr + mi * 16 + rE + e;
            int sw = (row & 7) << 4;
            #pragma unroll
            for (int ni = 0; ni < 4; ++ni) {
              float v = acc[mi][ni][e] + bv[ni];
              if (RELU) v = fmaxf(v, 0.f);
              int col = colh + ni * 16 + cA;
              *(float*)(cb + ((row * 512 + col * 4) ^ sw)) = v;
            }
          }
      }
      __builtin_amdgcn_s_barrier();
      #pragma unroll 4
      for (int r = 0; r < 16; ++r) {
        int row = wid * 32 + r * 2 + (lane >> 5);
        int gr = row0 + row;
        int addr = row * 512 + ((((lane & 31) * 16)) ^ ((row & 7) << 4));
        float4 v = *(const float4*)(cb + addr);
        if (gr - seg < cnt) {
          int pr = perm[gr];
          *(float4*)(OUT + (size_t)pr * NOUT + p * (NOUT / 2) + (lane & 31) * 4) = v;
        }
      }
      if (p == 0) __builtin_amdgcn_s_barrier();
    }
  }
}

// ---------------------------------------------------------------------------
// ABLATION (R10): layer-2 shape (K=512, NOUT=512), grid (2,128) = 1 block/CU,
// writes only dead ws scratch, launched AFTER production gemms.
// V0 full | V1 -epilogue | V2 -staging | V3 -ds_reads | V4 bars+MFMA | V5 MFMA.
// Non-epilogue variants keep MFMA live via acc-sum store (rule 17).
// ---------------------------------------------------------------------------
template <int V>
__launch_bounds__(512, 2)
__global__ void k_abl(const unsigned short* __restrict__ A,
                      const unsigned short* __restrict__ Wt,
                      float* __restrict__ scr,
                      unsigned short* __restrict__ Hs) {
  constexpr int K = 512, nKT = 8;
  constexpr bool READS  = (V == 0 || V == 1 || V == 2);
  constexpr bool STAGES = (V == 0 || V == 1 || V == 3);
  constexpr bool BARS   = (V != 5);
  constexpr bool EPI    = (V == 0);
  __shared__ char lds[131072];
  int tid = threadIdx.x, lane = tid & 63, wid = tid >> 6;
  int wr = (wid >> 2) * 128, wc = (wid & 3) * 64;
  int row0 = blockIdx.y * 256, col0 = blockIdx.x * 256;
  const char* Ag = (const char*)(A + (size_t)row0 * K);
  const char* Bg = (const char*)(Wt + (size_t)col0 * K);
  int gsrc = ((tid & 7) ^ ((tid >> 3) & 7)) * 16;
  const char* aS = Ag + (size_t)(tid >> 3) * (2 * K) + gsrc;
  const char* bS = Bg + (size_t)(((tid >> 3) & 31) + ((tid >> 3) >> 5) * 64) * (2 * K) + gsrc;
  auto stage = [&](int kt, int sub) {
    if (kt >= nKT) return;
    int h = sub & 1, du = kt & 1;
    char* dst = lds + ((sub < 2) ? 0 : 65536) + (du * 2 + h) * 16384 + wid * 1024;
    const char* src = (sub < 2 ? aS + (size_t)(h * 64) * (2 * K)
                               : bS + (size_t)(h * 32) * (2 * K)) + (size_t)kt * 128;
    async16(dst,        src);
    async16(dst + 8192, src + (size_t)128 * (2 * K));
  };
  f32x4 acc[8][4] = {};
  int rA = lane & 15, qoff = (lane >> 4) * 16, xr = (lane & 7) << 4;
  int lrA = (wid >> 2) * 64, clB = (wid & 3) * 32;
  bf16x8 a[4][2], b0[2][2], b1[2][2];

  if constexpr (STAGES) {
    stage(0, 0); stage(0, 1); stage(0, 2); stage(0, 3); stage(1, 0);
    asm volatile("s_waitcnt vmcnt(2)" ::: "memory");
  }
  if constexpr (BARS) __builtin_amdgcn_s_barrier();
  if constexpr (!READS) {   // one-time operand init; loop-invariant regs
    #pragma unroll
    for (int m = 0; m < 4; ++m) {
      int lr = lrA + m * 16 + rA;
      #pragma unroll
      for (int kk = 0; kk < 2; ++kk)
        a[m][kk] = *(const bf16x8*)(lds + ((lr * 128 + kk * 64 + qoff) ^ xr));
    }
    #pragma unroll
    for (int nn = 0; nn < 2; ++nn) {
      int cl = clB + nn * 16 + rA;
      #pragma unroll
      for (int kk = 0; kk < 2; ++kk) {
        b0[nn][kk] = *(const bf16x8*)(lds + 65536 + ((cl * 128 + kk * 64 + qoff) ^ xr));
        b1[nn][kk] = *(const bf16x8*)(lds + 65536 + 16384 + ((cl * 128 + kk * 64 + qoff) ^ xr));
      }
    }
    asm volatile("s_waitcnt lgkmcnt(0)" ::: "memory");
  }

  for (int g = 0; g < nKT; ++g) {
    int d = g & 1;
    const char* Ad = lds + d * 32768;
    const char* Bd = lds + 65536 + d * 32768;

    if constexpr (READS) {
      #pragma unroll
      for (int m = 0; m < 4; ++m) {
        int lr = lrA + m * 16 + rA;
        #pragma unroll
        for (int kk = 0; kk < 2; ++kk)
          a[m][kk] = *(const bf16x8*)(Ad + ((lr * 128 + kk * 64 + qoff) ^ xr));
      }
      #pragma unroll
      for (int nn = 0; nn < 2; ++nn) {
        int cl = clB + nn * 16 + rA;
        #pragma unroll
        for (int kk = 0; kk < 2; ++kk) {
          b0[nn][kk] = *(const bf16x8*)(Bd +         ((cl * 128 + kk * 64 + qoff) ^ xr));
          b1[nn][kk] = *(const bf16x8*)(Bd + 16384 + ((cl * 128 + kk * 64 + qoff) ^ xr));
        }
      }
    }
    if constexpr (STAGES) { stage(g + 1, 1); stage(g + 1, 2); stage(g + 1, 3); }
    if constexpr (BARS) {
      __builtin_amdgcn_s_barrier();
      asm volatile("s_waitcnt lgkmcnt(0)" ::: "memory");
    }
    __builtin_amdgcn_s_setprio(1);
    #pragma unroll
    for (int kk = 0; kk < 2; ++kk)
      #pragma unroll
      for (int m = 0; m < 4; ++m)
        #pragma unroll
        for (int nn = 0; nn < 2; ++nn) {
          acc[m][nn]     = __builtin_amdgcn_mfma_f32_16x16x32_bf16(a[m][kk], b0[nn][kk], acc[m][nn],     0, 0, 0);
          acc[m][2 + nn] = __builtin_amdgcn_mfma_f32_16x16x32_bf16(a[m][kk], b1[nn][kk], acc[m][2 + nn], 0, 0, 0);
        }
    __builtin_amdgcn_s_setprio(0);
    if constexpr (BARS) __builtin_amdgcn_s_barrier();

    if constexpr (READS) {
      #pragma unroll
      for (int m = 0; m < 4; ++m) {
        int lr = lrA + m * 16 + rA;
        #pragma unroll
        for (int kk = 0; kk < 2; ++kk)
          a[m][kk] = *(const bf16x8*)(Ad + 16384 + ((lr * 128 + kk * 64 + qoff) ^ xr));
      }
    }
    if constexpr (STAGES) stage(g + 2, 0);
    if constexpr (BARS) {
      __builtin_amdgcn_s_barrier();
      asm volatile("s_waitcnt lgkmcnt(0)" ::: "memory");
    }
    __builtin_amdgcn_s_setprio(1);
    #pragma unroll
    for (int kk = 0; kk < 2; ++kk)
      #pragma unroll
      for (int m = 0; m < 4; ++m)
        #pragma unroll
        for (int nn = 0; nn < 2; ++nn) {
          acc[4 + m][2 + nn] = __builtin_amdgcn_mfma_f32_16x16x32_bf16(a[m][kk], b1[nn][kk], acc[4 + m][2 + nn], 0, 0, 0);
          acc[4 + m][nn]     = __builtin_amdgcn_mfma_f32_16x16x32_bf16(a[m][kk], b0[nn][kk], acc[4 + m][nn],     0, 0, 0);
        }
    __builtin_amdgcn_s_setprio(0);
    if constexpr (STAGES) {
      if (g + 1 < nKT) {
        if (g + 2 < nKT) asm volatile("s_waitcnt vmcnt(2)" ::: "memory");
        else             asm volatile("s_waitcnt vmcnt(0)" ::: "memory");
      }
    }
    if constexpr (BARS) __builtin_amdgcn_s_barrier();
  }

  if constexpr (EPI) {
    int cA = lane & 15, rE = (lane >> 4) * 4;
    char* cb = (char*)lds;
    #pragma unroll
    for (int mi = 0; mi < 8; ++mi)
      #pragma unroll
      for (int e = 0; e < 4; ++e) {
        int row = wr + mi * 16 + rE + e;
        int sw = (row & 7) << 4;
        #pragma unroll
        for (int ni = 0; ni < 4; ++ni) {
          float v = fmaxf(acc[mi][ni][e], 0.f);
          int col = wc + ni * 16 + cA;
          *(unsigned short*)(cb + ((row * 512 + col * 2) ^ sw)) = f2bf(v);
        }
      }
    __builtin_amdgcn_s_barrier();
    #pragma unroll 4
    for (int r = 0; r < 16; ++r) {
      int row = wid * 32 + r * 2 + (lane >> 5);
      int addr = row * 512 + ((((lane & 31) * 16)) ^ ((row & 7) << 4));
      bf16x8 v = *(const bf16x8*)(cb + addr);
      *(bf16x8*)(Hs + (size_t)(row0 + row) * 512 + col0 + (lane & 31) * 8) = v;
    }
  } else {
    float s = 0.f;
    #pragma unroll
    for (int mi = 0; mi < 8; ++mi)
      #pragma unroll
      for (int ni = 0; ni < 4; ++ni)
        #pragma unroll
        for (int e = 0; e < 4; ++e) s += acc[mi][ni][e];
    scr[((size_t)(blockIdx.y * 2 + blockIdx.x)) * 512 + tid] = s;
  }
}

extern "C" void kernel_launch(void* const* d_in, const int* in_sizes, int n_in,
                              void* d_out, int out_size, void* d_ws, size_t ws_size,
                              hipStream_t stream) {
  const float* x     = (const float*)d_in[0];
  const int*   types = (const int*)d_in[1];
  const float* W0    = (const float*)d_in[2];
  const float* b0    = (const float*)d_in[3];
  const float* W1    = (const float*)d_in[4];
  const float* b1    = (const float*)d_in[5];
  const float* W2    = (const float*)d_in[6];
  const float* b2    = (const float*)d_in[7];
  float* out = (float*)d_out;
  int n = in_sizes[1];
  int RB = (n + 255) / 256 + TYPES;
  size_t NPAD = (size_t)RB * 256;

  char* ws = (char*)d_ws;
  int* meta = (int*)ws;
  int* perm = (int*)(ws + 1024);
  size_t off = 1024 + NPAD * 4;
  off = (off + 255) & ~(size_t)255;
  unsigned short* wt0 = (unsigned short*)(ws + off); off += (size_t)TYPES * D_H1 * D_IN * 2;
  unsigned short* wt1 = (unsigned short*)(ws + off); off += (size_t)TYPES * D_H2 * D_H1 * 2;
  unsigned short* wt2 = (unsigned short*)(ws + off); off += (size_t)TYPES * D_OUT * D_H2 * 2;
  off = (off + 255) & ~(size_t)255;
  unsigned short* B1 = (unsigned short*)(ws + off); off += NPAD * 512 * 2;
  unsigned short* B2 = (unsigned short*)(ws + off); off += NPAD * 512 * 2;

  int hb = (n + 255) / 256;
  k_init<<<1, 64, 0, stream>>>(meta);
  k_hist<<<hb, 256, 0, stream>>>(types, n, meta);
  k_scan<<<1, 64, 0, stream>>>(meta);
  k_scatter<<<hb, 256, 0, stream>>>(types, n, meta, perm);
  k_gather<<<RB * 32, 256, 0, stream>>>(x, perm, meta, B1);
  k_wtrans_all<<<1120, 256, 0, stream>>>(W0, W1, W2, wt0, wt1, wt2);

  k_gemm<D_IN, D_H1, true,  false><<<dim3(D_H1 / 256, RB), 512, 0, stream>>>(B1, wt0, b0, B2, nullptr, meta, perm);
  k_gemm<D_H1, D_H2, true,  false><<<dim3(D_H2 / 256, RB), 512, 0, stream>>>(B2, wt1, b1, B1, nullptr, meta, perm);
  k_gemm<D_H2, D_OUT, false, true ><<<dim3(D_OUT / 256, RB), 512, 0, stream>>>(B1, wt2, b2, nullptr, out, meta, perm);

  // Ablation dispatches (scratch only; B2/wt1 are dead after the final gemm).
  float* scr = (float*)B2;
  unsigned short* Hs = (unsigned short*)B2 + (16u << 20);  // +32MB offset
  k_abl<0><<<dim3(2, 128), 512, 0, stream>>>(B1, wt1, scr, Hs);
  k_abl<1><<<dim3(2, 128), 512, 0, stream>>>(B1, wt1, scr, Hs);
  k_abl<2><<<dim3(2, 128), 512, 0, stream>>>(B1, wt1, scr, Hs);
  k_abl<3><<<dim3(2, 128), 512, 0, stream>>>(B1, wt1, scr, Hs);
  k_abl<4><<<dim3(2, 128), 512, 0, stream>>>(B1, wt1, scr, Hs);
  k_abl<5><<<dim3(2, 128), 512, 0, stream>>>(B1, wt1, scr, Hs);
}

// Round 11
// 425.431 us; speedup vs baseline: 1.2041x; 1.2041x over previous
//
#include <hip/hip_runtime.h>
#include <stdint.h>

typedef float  f32x4  __attribute__((ext_vector_type(4)));
typedef short  bf16x8 __attribute__((ext_vector_type(8)));

#define TYPES 10
#define D_IN  128
#define D_H1  512
#define D_H2  512
#define D_OUT 256

__device__ __forceinline__ unsigned short f2bf(float f) {
  union { float f; unsigned u; } v; v.f = f;
  unsigned u = v.u;
  return (unsigned short)((u + 0x7FFFu + ((u >> 16) & 1u)) >> 16);  // RTNE
}

__device__ __forceinline__ void async16(void* lds, const void* g) {
  __builtin_amdgcn_global_load_lds(
      (const __attribute__((address_space(1))) void*)g,
      (__attribute__((address_space(3))) void*)lds, 16, 0, 0);
}

// meta layout (ints): [0..9] counts, [16..26] padded offsets (offs[10]=total), [32..41] scatter cursors
__global__ void k_init(int* meta) {
  if (threadIdx.x < 48) meta[threadIdx.x] = 0;
}

__global__ void k_hist(const int* __restrict__ types, int n, int* __restrict__ meta) {
  __shared__ int lc[TYPES];
  if (threadIdx.x < TYPES) lc[threadIdx.x] = 0;
  __syncthreads();
  int i = blockIdx.x * 256 + threadIdx.x;
  if (i < n) atomicAdd(&lc[types[i]], 1);
  __syncthreads();
  if (threadIdx.x < TYPES && lc[threadIdx.x]) atomicAdd(&meta[threadIdx.x], lc[threadIdx.x]);
}

__global__ void k_scan(int* meta) {
  if (threadIdx.x == 0) {
    int off = 0;
    for (int t = 0; t < TYPES; ++t) {
      meta[16 + t] = off;
      off += ((meta[t] + 255) >> 8) << 8;   // pad each segment to 256 rows (BM=256)
    }
    meta[26] = off;
  }
}

__global__ void k_scatter(const int* __restrict__ types, int n,
                          int* __restrict__ meta, int* __restrict__ perm) {
  __shared__ int lc[TYPES], lbase[TYPES];
  if (threadIdx.x < TYPES) lc[threadIdx.x] = 0;
  __syncthreads();
  int i = blockIdx.x * 256 + threadIdx.x;
  int t = 0, loc = 0;
  bool ok = i < n;
  if (ok) { t = types[i]; loc = atomicAdd(&lc[t], 1); }
  __syncthreads();
  if (threadIdx.x < TYPES) {
    int c = lc[threadIdx.x];
    lbase[threadIdx.x] = c ? atomicAdd(&meta[32 + threadIdx.x], c) : 0;
  }
  __syncthreads();
  if (ok) perm[meta[16 + t] + lbase[t] + loc] = i;
}

// gather rows into sorted order, fp32 -> bf16; zero the padding rows
__global__ void k_gather(const float* __restrict__ x, const int* __restrict__ perm,
                         const int* __restrict__ meta, unsigned short* __restrict__ xs) {
  int p = blockIdx.x * 8 + (threadIdx.x >> 5);
  if (p >= meta[26]) return;
  int t = 0;
  while (p >= meta[17 + t]) t++;
  int e = (threadIdx.x & 31) * 4;
  unsigned short o0, o1, o2, o3;
  if (p - meta[16 + t] < meta[t]) {
    const float4 v = *(const float4*)(x + (size_t)perm[p] * D_IN + e);
    o0 = f2bf(v.x); o1 = f2bf(v.y); o2 = f2bf(v.z); o3 = f2bf(v.w);
  } else {
    o0 = o1 = o2 = o3 = 0;
  }
  *(ushort4*)(xs + (size_t)p * D_IN + e) = make_ushort4(o0, o1, o2, o3);
}

// All three weight transposes in one launch: W[t] (K x NOUT) fp32 -> Wt[t] (NOUT x K) bf16
__global__ void k_wtrans_all(const float* __restrict__ W0a, const float* __restrict__ W1a,
                             const float* __restrict__ W2a,
                             unsigned short* __restrict__ wt0, unsigned short* __restrict__ wt1,
                             unsigned short* __restrict__ wt2) {
  int b = blockIdx.x;
  const float* W; unsigned short* Wt; int K, NOUT, t, local;
  if (b < 160)      { W = W0a; Wt = wt0; K = 128; NOUT = 512; t = b / 16; local = b % 16; }
  else if (b < 800) { b -= 160; W = W1a; Wt = wt1; K = 512; NOUT = 512; t = b / 64; local = b % 64; }
  else              { b -= 800; W = W2a; Wt = wt2; K = 512; NOUT = 256; t = b / 32; local = b % 32; }
  int ntn = NOUT >> 6;
  int kb = local / ntn, nb = local % ntn;
  __shared__ unsigned short tile[64][65];
  const float* src = W + (size_t)t * K * NOUT + (size_t)(kb * 64) * NOUT + nb * 64;
  int c = threadIdx.x & 63;
  int r0 = threadIdx.x >> 6;
  #pragma unroll
  for (int i = 0; i < 16; ++i) {
    int r = r0 * 16 + i;
    tile[r][c] = f2bf(src[(size_t)r * NOUT + c]);
  }
  __syncthreads();
  unsigned short* dst = Wt + (size_t)t * NOUT * K + (size_t)(nb * 64) * K + kb * 64;
  #pragma unroll
  for (int i = 0; i < 16; ++i) {
    int nn = r0 * 16 + i;
    dst[(size_t)nn * K + c] = tile[c][nn];
  }
}

// ---------------------------------------------------------------------------
// Grouped GEMM — faithful m201 template port (R11).
// 256x256 tile, BK=64, 512 thr = 8 waves (2Mx4N), per-wave 128x64 output.
// LDS 128KB: A halves [dbuf][h] 16KB at 0..64K (h = CONTIGUOUS rows h*128..),
// B halves at 64K..128K (cols h*128..). Each wave reads ONLY its own halves:
// ah = wid>>2 (its 128 rows), bh = (wid&3)>>1 (its col half); within-half col
// base (wid&1)*64.
// 4 phases per K-tile = (mh,kk) sub-steps of the wave's own output:
//  p0 (mh0,kk0): read a(4) + b0(kk0,4) + b1(kk1,4) = 12 rds; stage Ah1(g+1)
//  p1 (mh0,kk1): read a(4);                          stage Bh0(g+1)
//  p2 (mh1,kk0): read a(4);                          stage Bh1(g+1)
//  p3 (mh1,kk1): read a(4);                          stage Ah0(g+2)
// each phase: [reads; stage; (p0: lgkmcnt(8) pace); barrier; lgkmcnt(0);
//             setprio(1); 16 MFMA; setprio(0); (p3: vmcnt); barrier]
// Single wait per K-tile at end-p3 (FIFO ledger, nKT=2 and 8 simulated):
//  in-flight = [Ah1(g+1),Bh0(g+1),Bh1(g+1),Ah0(g+2)] -> drain through
//  Bh1(g+1): vmcnt(2) if g+2<nKT else vmcnt(0); no wait on last tile.
// Prologue: stage Ah0,Ah1,Bh0,Bh1(0),Ah0(1); vmcnt(2); barrier.
// Restage audit: every slot's restage is >=1 full phase (incl. that phase's
// lgkmcnt(0) + end barrier) after its last read; last-read phases: Ah0@p1... wait
//  Ah0 read p0,p1 (mh0); Ah1 read p2,p3; Bh0/Bh1 read p0 only. Stages: Ah1(g+1)
//  @(g)p0 vs Ah1(g-1) last read (g-1)p3: 1 phase+lgkm+bar. Bh0(g+1)@(g)p1 vs
//  read (g-1)p0: 5 phases. Bh1(g+1)@(g)p2: 6. Ah0(g+2)@(g)p3 vs read (g)p1: 2.
// XOR swizzle byte^=(lr&7)<<4 via pre-swizzled source granule (2-way max, free).
// acc[mi][n]: mi = mh*4+m' -> row offset (mi>>2)*64 + (mi&3)*16 (epilogue!).
// Epilogue: C staged through LDS (after full drain) for coalesced writes.
// ---------------------------------------------------------------------------
template <int K, int NOUT, bool RELU, bool FINAL>
__launch_bounds__(512, 2)
__global__ void k_gemm(const unsigned short* __restrict__ A,
                       const unsigned short* __restrict__ Wt,
                       const float* __restrict__ bias,
                       unsigned short* __restrict__ H,
                       float* __restrict__ OUT,
                       const int* __restrict__ meta,
                       const int* __restrict__ perm) {
  constexpr int nKT = K / 64;
  __shared__ char lds[131072];

  // bijective XCD-aware swizzle (m204)
  int NXB = gridDim.x;
  int nwg = NXB * (int)gridDim.y;
  int raw = blockIdx.x + blockIdx.y * NXB;
  int q = nwg >> 3, rr = nwg & 7;
  int xcd = raw & 7, idx = raw >> 3;
  int swz = (xcd < rr ? xcd * (q + 1) : rr * (q + 1) + (xcd - rr) * q) + idx;
  int bx = swz % NXB, by = swz / NXB;

  int row0 = by * 256;
  if (row0 >= meta[26]) return;          // block-uniform early exit
  int t = 0;
  while (row0 >= meta[17 + t]) t++;      // segment offsets are multiples of 256
  int seg = meta[16 + t], cnt = meta[t];
  int tid = threadIdx.x, lane = tid & 63, wid = tid >> 6;
  int wr = (wid >> 2) * 128, wc = (wid & 3) * 64;
  int ah = wid >> 2, bh = (wid & 3) >> 1, clb = (wid & 1) * 64;
  int col0 = bx * 256;
  const char* Ag = (const char*)(A + (size_t)row0 * K);
  const char* Bg = (const char*)(Wt + ((size_t)t * NOUT + col0) * K);

  // staging: per half-tile (128 rows x 64 K bf16 = 16KB), thread covers LDS
  // bytes i*8192 + tid*16 (i=0,1): lr = i*64 + (tid>>3), gl = tid&7;
  // source granule = gl ^ (lr&7) = (tid&7) ^ ((tid>>3)&7)  (i-independent).
  int gsrc = ((tid & 7) ^ ((tid >> 3) & 7)) * 16;
  const char* aS = Ag + (size_t)(tid >> 3) * (2 * K) + gsrc;
  const char* bS = Bg + (size_t)(tid >> 3) * (2 * K) + gsrc;

  // sub: 0=Ah0, 1=Ah1, 2=Bh0, 3=Bh1 (h = sub&1)
  auto stage = [&](int kt, int sub) {
    if (kt >= nKT) return;
    int h = sub & 1, du = kt & 1;
    char* dst = lds + ((sub < 2) ? 0 : 65536) + (du * 2 + h) * 16384 + wid * 1024;
    const char* base = (sub < 2) ? aS : bS;
    const char* src = base + (size_t)(h * 128) * (2 * K) + (size_t)kt * 128;
    async16(dst,        src);
    async16(dst + 8192, src + (size_t)64 * (2 * K));   // i=1: +64 rows
  };

  f32x4 acc[8][4] = {};
  int rA = lane & 15, qoff = (lane >> 4) * 16, xr = (lane & 7) << 4;

  // prologue: tile 0 complete + Ah0(1); drain tile 0 -> vmcnt(2)
  stage(0, 0); stage(0, 1); stage(0, 2); stage(0, 3); stage(1, 0);
  asm volatile("s_waitcnt vmcnt(2)" ::: "memory");
  __builtin_amdgcn_s_barrier();

  for (int g = 0; g < nKT; ++g) {
    int d = g & 1;
    const char* Au = lds + (d * 2 + ah) * 16384;           // wave's own A-half
    const char* Bu = lds + 65536 + (d * 2 + bh) * 16384;   // wave's own B-half
    bf16x8 a[4], b0[4], b1[4];

    // ---- p0: (mh0, kk0) — 12 reads ----
    #pragma unroll
    for (int m = 0; m < 4; ++m) {
      int lr = m * 16 + rA;
      a[m] = *(const bf16x8*)(Au + lr * 128 + (qoff ^ xr));
    }
    #pragma unroll
    for (int n = 0; n < 4; ++n) {
      int cl = clb + n * 16 + rA;
      b0[n] = *(const bf16x8*)(Bu + cl * 128 + (qoff ^ xr));
      b1[n] = *(const bf16x8*)(Bu + cl * 128 + ((64 + qoff) ^ xr));
    }
    stage(g + 1, 1);                      // Ah1(g+1)
    asm volatile("s_waitcnt lgkmcnt(8)" ::: "memory");   // pace the 12-read burst
    __builtin_amdgcn_s_barrier();
    asm volatile("s_waitcnt lgkmcnt(0)" ::: "memory");
    __builtin_amdgcn_s_setprio(1);
    #pragma unroll
    for (int m = 0; m < 4; ++m)
      #pragma unroll
      for (int n = 0; n < 4; ++n)
        acc[m][n] = __builtin_amdgcn_mfma_f32_16x16x32_bf16(a[m], b0[n], acc[m][n], 0, 0, 0);
    __builtin_amdgcn_s_setprio(0);
    __builtin_amdgcn_s_barrier();

    // ---- p1: (mh0, kk1) — 4 reads ----
    #pragma unroll
    for (int m = 0; m < 4; ++m) {
      int lr = m * 16 + rA;
      a[m] = *(const bf16x8*)(Au + lr * 128 + ((64 + qoff) ^ xr));
    }
    stage(g + 1, 2);                      // Bh0(g+1)
    __builtin_amdgcn_s_barrier();
    asm volatile("s_waitcnt lgkmcnt(0)" ::: "memory");
    __builtin_amdgcn_s_setprio(1);
    #pragma unroll
    for (int m = 0; m < 4; ++m)
      #pragma unroll
      for (int n = 0; n < 4; ++n)
        acc[m][n] = __builtin_amdgcn_mfma_f32_16x16x32_bf16(a[m], b1[n], acc[m][n], 0, 0, 0);
    __builtin_amdgcn_s_setprio(0);
    __builtin_amdgcn_s_barrier();

    // ---- p2: (mh1, kk0) — 4 reads ----
    #pragma unroll
    for (int m = 0; m < 4; ++m) {
      int lr = 64 + m * 16 + rA;
      a[m] = *(const bf16x8*)(Au + lr * 128 + (qoff ^ xr));
    }
    stage(g + 1, 3);                      // Bh1(g+1)
    __builtin_amdgcn_s_barrier();
    asm volatile("s_waitcnt lgkmcnt(0)" ::: "memory");
    __builtin_amdgcn_s_setprio(1);
    #pragma unroll
    for (int m = 0; m < 4; ++m)
      #pragma unroll
      for (int n = 0; n < 4; ++n)
        acc[4 + m][n] = __builtin_amdgcn_mfma_f32_16x16x32_bf16(a[m], b0[n], acc[4 + m][n], 0, 0, 0);
    __builtin_amdgcn_s_setprio(0);
    __builtin_amdgcn_s_barrier();

    // ---- p3: (mh1, kk1) — 4 reads ----
    #pragma unroll
    for (int m = 0; m < 4; ++m) {
      int lr = 64 + m * 16 + rA;
      a[m] = *(const bf16x8*)(Au + lr * 128 + ((64 + qoff) ^ xr));
    }
    stage(g + 2, 0);                      // Ah0(g+2)
    __builtin_amdgcn_s_barrier();
    asm volatile("s_waitcnt lgkmcnt(0)" ::: "memory");
    __builtin_amdgcn_s_setprio(1);
    #pragma unroll
    for (int m = 0; m < 4; ++m)
      #pragma unroll
      for (int n = 0; n < 4; ++n)
        acc[4 + m][n] = __builtin_amdgcn_mfma_f32_16x16x32_bf16(a[m], b1[n], acc[4 + m][n], 0, 0, 0);
    __builtin_amdgcn_s_setprio(0);
    if (g + 1 < nKT) {
      if (g + 2 < nKT) asm volatile("s_waitcnt vmcnt(2)" ::: "memory");
      else             asm volatile("s_waitcnt vmcnt(0)" ::: "memory");
    }
    __builtin_amdgcn_s_barrier();
  }
  // loop exit: all vmem drained; all waves past the final barrier.

  // epilogue: acc -> LDS (XOR-swizzled 16B granules) -> coalesced stores.
  // acc row offset: (mi>>2)*64 + (mi&3)*16 (m201 phase order).
  int cA = lane & 15, rE = (lane >> 4) * 4;
  float bv[4];
  #pragma unroll
  for (int ni = 0; ni < 4; ++ni) bv[ni] = bias[t * NOUT + col0 + wc + ni * 16 + cA];
  char* cb = (char*)lds;

  if (!FINAL) {
    #pragma unroll
    for (int mi = 0; mi < 8; ++mi) {
      int rowoff = (mi >> 2) * 64 + (mi & 3) * 16;
      #pragma unroll
      for (int e = 0; e < 4; ++e) {
        int row = wr + rowoff + rE + e;
        int sw = (row & 7) << 4;
        #pragma unroll
        for (int ni = 0; ni < 4; ++ni) {
          float v = acc[mi][ni][e] + bv[ni];
          if (RELU) v = fmaxf(v, 0.f);
          int col = wc + ni * 16 + cA;
          *(unsigned short*)(cb + ((row * 512 + col * 2) ^ sw)) = f2bf(v);
        }
      }
    }
    __builtin_amdgcn_s_barrier();
    #pragma unroll 4
    for (int r = 0; r < 16; ++r) {
      int row = wid * 32 + r * 2 + (lane >> 5);
      int addr = row * 512 + ((((lane & 31) * 16)) ^ ((row & 7) << 4));
      bf16x8 v = *(const bf16x8*)(cb + addr);
      *(bf16x8*)(H + (size_t)(row0 + row) * NOUT + col0 + (lane & 31) * 8) = v;
    }
  } else {
    int myhalf = (wid & 3) >> 1;
    #pragma unroll
    for (int p = 0; p < 2; ++p) {
      if (myhalf == p) {
        int colh = wc & 127;
        #pragma unroll
        for (int mi = 0; mi < 8; ++mi) {
          int rowoff = (mi >> 2) * 64 + (mi & 3) * 16;
          #pragma unroll
          for (int e = 0; e < 4; ++e) {
            int row = wr + rowoff + rE + e;
            int sw = (row & 7) << 4;
            #pragma unroll
            for (int ni = 0; ni < 4; ++ni) {
              float v = acc[mi][ni][e] + bv[ni];
              if (RELU) v = fmaxf(v, 0.f);
              int col = colh + ni * 16 + cA;
              *(float*)(cb + ((row * 512 + col * 4) ^ sw)) = v;
            }
          }
        }
      }
      __builtin_amdgcn_s_barrier();
      #pragma unroll 4
      for (int r = 0; r < 16; ++r) {
        int row = wid * 32 + r * 2 + (lane >> 5);
        int gr = row0 + row;
        int addr = row * 512 + ((((lane & 31) * 16)) ^ ((row & 7) << 4));
        float4 v = *(const float4*)(cb + addr);
        if (gr - seg < cnt) {
          int pr = perm[gr];
          *(float4*)(OUT + (size_t)pr * NOUT + p * (NOUT / 2) + (lane & 31) * 4) = v;
        }
      }
      if (p == 0) __builtin_amdgcn_s_barrier();
    }
  }
}

extern "C" void kernel_launch(void* const* d_in, const int* in_sizes, int n_in,
                              void* d_out, int out_size, void* d_ws, size_t ws_size,
                              hipStream_t stream) {
  const float* x     = (const float*)d_in[0];
  const int*   types = (const int*)d_in[1];
  const float* W0    = (const float*)d_in[2];
  const float* b0    = (const float*)d_in[3];
  const float* W1    = (const float*)d_in[4];
  const float* b1    = (const float*)d_in[5];
  const float* W2    = (const float*)d_in[6];
  const float* b2    = (const float*)d_in[7];
  float* out = (float*)d_out;
  int n = in_sizes[1];
  int RB = (n + 255) / 256 + TYPES;       // worst-case padded 256-row blocks
  size_t NPAD = (size_t)RB * 256;

  char* ws = (char*)d_ws;
  int* meta = (int*)ws;
  int* perm = (int*)(ws + 1024);
  size_t off = 1024 + NPAD * 4;
  off = (off + 255) & ~(size_t)255;
  unsigned short* wt0 = (unsigned short*)(ws + off); off += (size_t)TYPES * D_H1 * D_IN * 2;
  unsigned short* wt1 = (unsigned short*)(ws + off); off += (size_t)TYPES * D_H2 * D_H1 * 2;
  unsigned short* wt2 = (unsigned short*)(ws + off); off += (size_t)TYPES * D_OUT * D_H2 * 2;
  off = (off + 255) & ~(size_t)255;
  unsigned short* B1 = (unsigned short*)(ws + off); off += NPAD * 512 * 2;  // xs, later h2
  unsigned short* B2 = (unsigned short*)(ws + off); off += NPAD * 512 * 2;  // h1

  int hb = (n + 255) / 256;
  k_init<<<1, 64, 0, stream>>>(meta);
  k_hist<<<hb, 256, 0, stream>>>(types, n, meta);
  k_scan<<<1, 64, 0, stream>>>(meta);
  k_scatter<<<hb, 256, 0, stream>>>(types, n, meta, perm);
  k_gather<<<RB * 32, 256, 0, stream>>>(x, perm, meta, B1);
  k_wtrans_all<<<1120, 256, 0, stream>>>(W0, W1, W2, wt0, wt1, wt2);

  k_gemm<D_IN, D_H1, true,  false><<<dim3(D_H1 / 256, RB), 512, 0, stream>>>(B1, wt0, b0, B2, nullptr, meta, perm);
  k_gemm<D_H1, D_H2, true,  false><<<dim3(D_H2 / 256, RB), 512, 0, stream>>>(B2, wt1, b1, B1, nullptr, meta, perm);
  k_gemm<D_H2, D_OUT, false, true ><<<dim3(D_OUT / 256, RB), 512, 0, stream>>>(B1, wt2, b2, nullptr, out, meta, perm);
}